// Round 12
// baseline (88.479 us; speedup 1.0000x reference)
//
#include <hip/hip_runtime.h>
#include <hip/hip_bf16.h>
#include <cstdint>

// Problem dims (fixed by reference)
#define G_ 256
#define P_ 1024
#define D_ 128
#define K_ 16
#define H_ 32
#define N_ (G_ * P_)

// d_out layout (floats), in reference return order
constexpr size_t OFF_COARSE = 0;                               // [G*K, D] = 524288
constexpr size_t OFF_ASSIGN = (size_t)G_ * K_ * D_;            // 524288
constexpr size_t OFF_SEND   = OFF_ASSIGN + (size_t)N_ * K_;    // 4718592
constexpr size_t OFF_RECV   = OFF_SEND + (size_t)G_ * K_ * K_; // 4784128
constexpr size_t OFF_EDGE   = OFF_RECV + (size_t)G_ * K_ * K_; // 4849664

typedef __attribute__((ext_vector_type(8))) short bf16x8;   // 8 bf16 (4 VGPR)
typedef __attribute__((ext_vector_type(4))) float f32x4;    // MFMA C/D

// round-to-nearest f32 -> bf16 pair packed in u32 (low = a, high = b)
__device__ __forceinline__ unsigned rpack(float a, float b) {
    const unsigned ua = __float_as_uint(a) + 0x8000u;
    const unsigned ub = __float_as_uint(b) + 0x8000u;
    return (ua >> 16) | (ub & 0xffff0000u);
}
__device__ __forceinline__ short rbf16(float a) {
    return (short)((__float_as_uint(a) + 0x8000u) >> 16);
}

union FragU { uint4 u; bf16x8 v; };

// ---------------------------------------------------------------------------
// Kernel 1 (v7b): block-cooperative staged MFMA MLP + softmax.
// R11 postmortem (first clean mlp counters): WRITE_SIZE 133 MB vs 16.8 MB
// output = ld[8] spilled to scratch (VGPR_Count 68 — launch_bounds(256,3)
// starved the allocator; 128 B/thread x 3 steps x 262K threads ~ 100 MB).
// v7b = R11 byte-identical EXCEPT __launch_bounds__(256,2): ~120 VGPR fits,
// no spill; occupancy still LDS-bound at 3 blocks/CU (48 KB) = 12 waves/CU.
// Design recap: per step, 256 threads stage 64 nodes (32 KB) into XOR-
// swizzled LDS with DENSE lane-contiguous float4 loads (issued BEFORE the
// compute of the current step -> fly under compute+barrier, T14); each wave
// reads its 16-node fragment tile (swizzle both sides, rule 21) and runs the
// R10-validated compute (1x bf16-RN MFMA, h LDS roundtrip, no-max softmax).
// Fragment maps (16x16x32 bf16, HW-validated R5-R11): A row=lane&15,
// k=(lane>>4)*8+e; B col=lane&15; C/D col=lane&15, row=(lane>>4)*4+reg.
// ---------------------------------------------------------------------------
__global__ __launch_bounds__(256, 2) void mlp_assign_mfma(
    const float* __restrict__ x, const float* __restrict__ W1,
    const float* __restrict__ b1, const float* __restrict__ W2,
    const float* __restrict__ b2, float* __restrict__ assign_out)
{
    __shared__ float    xstage[4 * 16 * 128];  // 32 KB: [wave][16 rows][128 f], swz
    __shared__ short    w1s[4096];             // 8 KB: frag order
    __shared__ unsigned hstage[4][512];        // per-wave 2 KB (R8-validated layout)

    const int tid  = threadIdx.x;
    const int lane = tid & 63;
    const int wave = tid >> 6;
    const int q = lane >> 4;   // 0..3
    const int c = lane & 15;   // 0..15

    const size_t blockbase = (size_t)blockIdx.x * 256;

    // ---- stage W1 (bf16-RN) into LDS in fragment order ----
    for (int i = tid; i < 4096; i += 256) {
        const int e  = i & 7;
        const int cc = (i >> 3) & 15;
        const int qq = (i >> 7) & 3;
        const int nt = (i >> 9) & 1;
        const int kb = (i >> 10) & 3;
        w1s[(((kb * 2 + nt) * 4 + qq) * 16 + cc) * 8 + e] =
            rbf16(W1[(kb * 32 + qq * 8 + e) * H_ + nt * 16 + cc]);
    }

    // ---- W2 fragment in registers (k=j=q*8+e, col=c) ----
    FragU w2f;
    {
        float wv[8];
#pragma unroll
        for (int e = 0; e < 8; ++e) wv[e] = W2[(q * 8 + e) * K_ + c];
        w2f.u = make_uint4(rpack(wv[0], wv[1]), rpack(wv[2], wv[3]),
                           rpack(wv[4], wv[5]), rpack(wv[6], wv[7]));
    }
    const float b1v0 = b1[c];
    const float b1v1 = b1[16 + c];
    const float b2v  = b2[c];
    unsigned* hw = hstage[wave];

    // staging address precompute: thread handles float4 ids v = i*256+tid
    // v in [0,2048): row64 = v>>5, slot = v&31
    // LDS byte = (row64>>4)*8192 + ((row64&15)*512 + slot*16) ^ ((row64&7)<<4)
    int sbyte[8];
#pragma unroll
    for (int i = 0; i < 8; ++i) {
        const int v = i * 256 + tid;
        const int row64 = v >> 5;
        const int slot  = v & 31;
        sbyte[i] = (row64 >> 4) * 8192 +
                   ((((row64 & 15) * 512) + slot * 16) ^ ((row64 & 7) << 4));
    }

    // ---- prologue: stage step 0 ----
    float4 ld[8];
    {
        const float4* src = (const float4*)(x + blockbase * D_);
#pragma unroll
        for (int i = 0; i < 8; ++i) ld[i] = src[i * 256 + tid];
#pragma unroll
        for (int i = 0; i < 8; ++i)
            *(float4*)((char*)xstage + sbyte[i]) = ld[i];
    }
    __syncthreads();

    // fragment read offsets (swz applied to full logical addr; rule 21)
    const int fragbase = wave * 8192;
    const int csw = (c & 7) << 4;

#pragma unroll 1
    for (int t = 0; t < 4; ++t) {
        // ---- issue next step's global loads (fly under compute below) ----
        if (t < 3) {
            const float4* src = (const float4*)(x + (blockbase + (size_t)(t + 1) * 64) * D_);
#pragma unroll
            for (int i = 0; i < 8; ++i) ld[i] = src[i * 256 + tid];
        }

        // ---- compute: wave's 16 nodes from swizzled LDS tile ----
        FragU af[4];
#pragma unroll
        for (int kb = 0; kb < 4; ++kb) {
            const int p0 = c * 512 + kb * 128 + q * 32;
            const float4 v0 = *(const float4*)((char*)xstage + fragbase + (p0 ^ csw));
            const float4 v1 = *(const float4*)((char*)xstage + fragbase + ((p0 + 16) ^ csw));
            af[kb].u = make_uint4(rpack(v0.x, v0.y), rpack(v0.z, v0.w),
                                  rpack(v1.x, v1.y), rpack(v1.z, v1.w));
        }

        f32x4 acc0 = {b1v0, b1v0, b1v0, b1v0};
        f32x4 acc1 = {b1v1, b1v1, b1v1, b1v1};
#pragma unroll
        for (int kb = 0; kb < 4; ++kb) {
            const bf16x8 bh0 = *(const bf16x8*)&w1s[((kb * 2 + 0) * 4 + q) * 128 + c * 8];
            const bf16x8 bh1 = *(const bf16x8*)&w1s[((kb * 2 + 1) * 4 + q) * 128 + c * 8];
            acc0 = __builtin_amdgcn_mfma_f32_16x16x32_bf16(af[kb].v, bh0, acc0, 0, 0, 0);
            acc1 = __builtin_amdgcn_mfma_f32_16x16x32_bf16(af[kb].v, bh1, acc1, 0, 0, 0);
        }

        // relu + park h (bf16 in u32 slots) in wave-private swizzled LDS
#pragma unroll
        for (int r = 0; r < 4; ++r) {
            const int row = q * 4 + r;
            const int xsw = (row & 7) << 2;
            hw[(row * 32 + c) ^ xsw] =
                (unsigned)(unsigned short)rbf16(fmaxf(acc0[r], 0.f));
            hw[(row * 32 + 16 + c) ^ xsw] =
                (unsigned)(unsigned short)rbf16(fmaxf(acc1[r], 0.f));
        }

        // layer 2 A-frag: node=c, j=q*8+e (offsets INSIDE the XOR)
        const int hsw = (c & 7) << 2;
        const uint4 u0 = *(const uint4*)&hw[(c * 32 + q * 8) ^ hsw];
        const uint4 u1 = *(const uint4*)&hw[(c * 32 + q * 8 + 4) ^ hsw];
        FragU ha;
        ha.u.x = (u0.x & 0xffffu) | (u0.y << 16);
        ha.u.y = (u0.z & 0xffffu) | (u0.w << 16);
        ha.u.z = (u1.x & 0xffffu) | (u1.y << 16);
        ha.u.w = (u1.z & 0xffffu) | (u1.w << 16);

        f32x4 lacc = {b2v, b2v, b2v, b2v};
        lacc = __builtin_amdgcn_mfma_f32_16x16x32_bf16(ha.v, w2f.v, lacc, 0, 0, 0);

        // softmax over K=16 (no max-subtract; |logit| small), store
        float ex0 = __expf(lacc[0]);
        float ex1 = __expf(lacc[1]);
        float ex2 = __expf(lacc[2]);
        float ex3 = __expf(lacc[3]);
        float s0 = ex0, s1 = ex1, s2 = ex2, s3 = ex3;
#pragma unroll
        for (int s = 1; s < 16; s <<= 1) {
            s0 += __shfl_xor(s0, s, 16);
            s1 += __shfl_xor(s1, s, 16);
            s2 += __shfl_xor(s2, s, 16);
            s3 += __shfl_xor(s3, s, 16);
        }
        const size_t node0 = blockbase + (size_t)t * 64 + (size_t)wave * 16 + q * 4;
        const size_t ob = node0 * K_ + c;
        assign_out[ob + 0 * K_] = ex0 / s0;
        assign_out[ob + 1 * K_] = ex1 / s1;
        assign_out[ob + 2 * K_] = ex2 / s2;
        assign_out[ob + 3 * K_] = ex3 / s3;

        // ---- rotate single LDS buffer: drain reads, write next step ----
        __syncthreads();
        if (t < 3) {
#pragma unroll
            for (int i = 0; i < 8; ++i)
                *(float4*)((char*)xstage + sbyte[i]) = ld[i];
        }
        __syncthreads();
    }
}

// ---------------------------------------------------------------------------
// Kernel 2 (v4): coarse segment-sum + fused edge writer (unchanged, ~6 us).
// ---------------------------------------------------------------------------
#define FMA4(dst, v, sc)                                                      \
    dst.x = fmaf(v.x, sc, dst.x); dst.y = fmaf(v.y, sc, dst.y);               \
    dst.z = fmaf(v.z, sc, dst.z); dst.w = fmaf(v.w, sc, dst.w)

__global__ __launch_bounds__(1024, 4) void coarse_kernel(
    const float* __restrict__ x, const float* __restrict__ assign,
    const int* __restrict__ n_node, float* __restrict__ out)
{
    __shared__ float xs[2][32 * 128];
    __shared__ float as_[2][32 * 16];
    __shared__ int pref[G_];

    const int tid = threadIdx.x;
    const int g = blockIdx.x;

    if (tid < 256) {
        const int e = g * 256 + tid;
        out[OFF_SEND + e] = (float)(g * K_ + (tid >> 4));
        out[OFF_RECV + e] = (float)(g * K_ + (tid & 15));
        out[OFF_EDGE + e] = 1.0f;
    }

    if (tid < G_) pref[tid] = n_node[tid];
    __syncthreads();
    for (int st = 1; st < G_; st <<= 1) {
        int v = 0;
        if (tid < G_ && tid >= st) v = pref[tid - st];
        __syncthreads();
        if (tid < G_ && tid >= st) pref[tid] += v;
        __syncthreads();
    }
    const int start = (g == 0) ? 0 : min(pref[g - 1], N_);
    const int end   = (g == G_ - 1) ? N_ : min(pref[g], N_);

    const int dq = tid & 31;
    const int s  = tid >> 5;

    float4 acc[K_];
#pragma unroll
    for (int k = 0; k < K_; ++k) acc[k] = make_float4(0.f, 0.f, 0.f, 0.f);

    const int total = end - start;
    const int nfull = total >> 5;
    const int tail  = total & 31;

    float4 rx = make_float4(0.f, 0.f, 0.f, 0.f);
    float4 ra = make_float4(0.f, 0.f, 0.f, 0.f);
    if (nfull > 0) {
        rx = *(const float4*)(x + (size_t)start * D_ + tid * 4);
        if (tid < 128)
            ra = *(const float4*)(assign + (size_t)start * K_ + tid * 4);
    }

    int b = 0;
    for (int cc = 0; cc < nfull; ++cc) {
        *(float4*)(&xs[b][tid * 4]) = rx;
        if (tid < 128) *(float4*)(&as_[b][tid * 4]) = ra;
        __syncthreads();

        if (cc + 1 < nfull) {
            const size_t nb = (size_t)start + (size_t)(cc + 1) * 32;
            rx = *(const float4*)(x + nb * D_ + tid * 4);
            if (tid < 128)
                ra = *(const float4*)(assign + nb * K_ + tid * 4);
        }

        const float4 xv = *(const float4*)(&xs[b][s * D_ + dq * 4]);
        const float4* av = (const float4*)(&as_[b][s * K_]);
#pragma unroll
        for (int qq = 0; qq < 4; ++qq) {
            const float4 a = av[qq];
            FMA4(acc[4 * qq + 0], xv, a.x);
            FMA4(acc[4 * qq + 1], xv, a.y);
            FMA4(acc[4 * qq + 2], xv, a.z);
            FMA4(acc[4 * qq + 3], xv, a.w);
        }
        b ^= 1;
    }

    if (tail > 0 && s < tail) {
        const size_t n = (size_t)start + (size_t)nfull * 32 + s;
        const float4 xv = *(const float4*)(x + n * D_ + dq * 4);
        const float4* av = (const float4*)(assign + n * K_);
#pragma unroll
        for (int qq = 0; qq < 4; ++qq) {
            const float4 a = av[qq];
            FMA4(acc[4 * qq + 0], xv, a.x);
            FMA4(acc[4 * qq + 1], xv, a.y);
            FMA4(acc[4 * qq + 2], xv, a.z);
            FMA4(acc[4 * qq + 3], xv, a.w);
        }
    }

    __syncthreads();
    float* red = &xs[0][0];
#pragma unroll
    for (int k = 0; k < K_; ++k) {
        *(float4*)(&red[s * D_ + dq * 4]) = acc[k];
        __syncthreads();
        if (tid < D_) {
            float sum = 0.f;
#pragma unroll
            for (int ss = 0; ss < 32; ++ss) sum += red[ss * D_ + tid];
            out[OFF_COARSE + ((size_t)g * K_ + k) * D_ + tid] = sum;
        }
        __syncthreads();
    }
}

extern "C" void kernel_launch(void* const* d_in, const int* in_sizes, int n_in,
                              void* d_out, int out_size, void* d_ws, size_t ws_size,
                              hipStream_t stream)
{
    const float* x      = (const float*)d_in[0];
    const float* W1     = (const float*)d_in[1];
    const float* b1     = (const float*)d_in[2];
    const float* W2     = (const float*)d_in[3];
    const float* b2     = (const float*)d_in[4];
    const int*   n_node = (const int*)d_in[5];
    float* out = (float*)d_out;

    mlp_assign_mfma<<<N_ / 256, 256, 0, stream>>>(x, W1, b1, W2, b2, out + OFF_ASSIGN);
    coarse_kernel<<<G_, 1024, 0, stream>>>(x, out + OFF_ASSIGN, n_node, out);
}

// Round 13
// 86.354 us; speedup vs baseline: 1.0246x; 1.0246x over previous
//
#include <hip/hip_runtime.h>
#include <hip/hip_bf16.h>
#include <cstdint>

// Problem dims (fixed by reference)
#define G_ 256
#define P_ 1024
#define D_ 128
#define K_ 16
#define H_ 32
#define N_ (G_ * P_)

// d_out layout (floats), in reference return order
constexpr size_t OFF_COARSE = 0;                               // [G*K, D] = 524288
constexpr size_t OFF_ASSIGN = (size_t)G_ * K_ * D_;            // 524288
constexpr size_t OFF_SEND   = OFF_ASSIGN + (size_t)N_ * K_;    // 4718592
constexpr size_t OFF_RECV   = OFF_SEND + (size_t)G_ * K_ * K_; // 4784128
constexpr size_t OFF_EDGE   = OFF_RECV + (size_t)G_ * K_ * K_; // 4849664

typedef __attribute__((ext_vector_type(8))) short bf16x8;   // 8 bf16 (4 VGPR)
typedef __attribute__((ext_vector_type(4))) float f32x4;    // MFMA C/D

// round-to-nearest f32 -> bf16 pair packed in u32 (low = a, high = b)
__device__ __forceinline__ unsigned rpack(float a, float b) {
    const unsigned ua = __float_as_uint(a) + 0x8000u;
    const unsigned ub = __float_as_uint(b) + 0x8000u;
    return (ua >> 16) | (ub & 0xffff0000u);
}
__device__ __forceinline__ short rbf16(float a) {
    return (short)((__float_as_uint(a) + 0x8000u) >> 16);
}

union FragU { uint4 u; bf16x8 v; };

// ---------------------------------------------------------------------------
// Kernel 1 (v7c): block-cooperative staged MFMA MLP + softmax.
// R11/R12 postmortem: ld[8] held across a RUNTIME `if (t<3)` inside a
// `#pragma unroll 1` loop -> hipcc demoted the array to scratch (VGPR=68,
// WRITE_SIZE 133 MB, unchanged by launch_bounds). R8's clean compile
// (WRITE_SIZE exactly 16.4 MB) used macro-unrolled steps with COMPILE-TIME
// prefetch literals -> v7c restores that shape: 4 explicit steps, literal
// DO_PREF, unconditional ld assignment per step.
// Design: per step, 256 threads stage 64 nodes (32 KB) into XOR-swizzled
// LDS with DENSE lane-contiguous float4 loads (issued before compute, fly
// under compute+barrier); each wave reads its 16-node fragment tile
// (swizzle both sides) and runs the R10-validated compute path (1x bf16-RN
// MFMA, h LDS roundtrip, no-max softmax). 48 KB LDS -> 3 blocks/CU.
// Fragment maps (16x16x32 bf16, HW-validated R5-R12): A row=lane&15,
// k=(lane>>4)*8+e; B col=lane&15; C/D col=lane&15, row=(lane>>4)*4+reg.
// ---------------------------------------------------------------------------
__global__ __launch_bounds__(256, 3) void mlp_assign_mfma(
    const float* __restrict__ x, const float* __restrict__ W1,
    const float* __restrict__ b1, const float* __restrict__ W2,
    const float* __restrict__ b2, float* __restrict__ assign_out)
{
    __shared__ float    xstage[4 * 16 * 128];  // 32 KB: [wave][16 rows][128 f], swz
    __shared__ short    w1s[4096];             // 8 KB: frag order
    __shared__ unsigned hstage[4][512];        // per-wave 2 KB (R8-validated layout)

    const int tid  = threadIdx.x;
    const int lane = tid & 63;
    const int wave = tid >> 6;
    const int q = lane >> 4;   // 0..3
    const int c = lane & 15;   // 0..15

    const size_t blockbase = (size_t)blockIdx.x * 256;

    // ---- stage W1 (bf16-RN) into LDS in fragment order ----
    for (int i = tid; i < 4096; i += 256) {
        const int e  = i & 7;
        const int cc = (i >> 3) & 15;
        const int qq = (i >> 7) & 3;
        const int nt = (i >> 9) & 1;
        const int kb = (i >> 10) & 3;
        w1s[(((kb * 2 + nt) * 4 + qq) * 16 + cc) * 8 + e] =
            rbf16(W1[(kb * 32 + qq * 8 + e) * H_ + nt * 16 + cc]);
    }

    // ---- W2 fragment in registers (k=j=q*8+e, col=c) ----
    FragU w2f;
    {
        float wv[8];
#pragma unroll
        for (int e = 0; e < 8; ++e) wv[e] = W2[(q * 8 + e) * K_ + c];
        w2f.u = make_uint4(rpack(wv[0], wv[1]), rpack(wv[2], wv[3]),
                           rpack(wv[4], wv[5]), rpack(wv[6], wv[7]));
    }
    const float b1v0 = b1[c];
    const float b1v1 = b1[16 + c];
    const float b2v  = b2[c];
    unsigned* hw = hstage[wave];

    // staging address precompute: thread handles float4 ids v = i*256+tid
    // LDS byte = (row64>>4)*8192 + ((row64&15)*512 + slot*16) ^ ((row64&7)<<4)
    int sbyte[8];
#pragma unroll
    for (int i = 0; i < 8; ++i) {
        const int v = i * 256 + tid;
        const int row64 = v >> 5;
        const int slot  = v & 31;
        sbyte[i] = (row64 >> 4) * 8192 +
                   ((((row64 & 15) * 512) + slot * 16) ^ ((row64 & 7) << 4));
    }

    const int fragbase = wave * 8192;
    const int csw = (c & 7) << 4;

    float4 ld[8];

    // ---- prologue: stage step 0 ----
    {
        const float4* src = (const float4*)(x + blockbase * D_);
#pragma unroll
        for (int i = 0; i < 8; ++i) ld[i] = src[i * 256 + tid];
#pragma unroll
        for (int i = 0; i < 8; ++i)
            *(float4*)((char*)xstage + sbyte[i]) = ld[i];
    }
    __syncthreads();

#define STEP(MT, DO_PREF)                                                     \
    {                                                                         \
        if (DO_PREF) {  /* literal -> unconditional assignment, stays SSA */  \
            const float4* src =                                               \
                (const float4*)(x + (blockbase + (size_t)((MT) + 1) * 64) * D_); \
            _Pragma("unroll")                                                 \
            for (int i = 0; i < 8; ++i) ld[i] = src[i * 256 + tid];           \
        }                                                                     \
        /* compute: wave's 16 nodes from swizzled LDS tile */                 \
        FragU af[4];                                                          \
        _Pragma("unroll")                                                     \
        for (int kb = 0; kb < 4; ++kb) {                                      \
            const int p0 = c * 512 + kb * 128 + q * 32;                       \
            const float4 v0 = *(const float4*)((char*)xstage + fragbase + (p0 ^ csw)); \
            const float4 v1 = *(const float4*)((char*)xstage + fragbase + ((p0 + 16) ^ csw)); \
            af[kb].u = make_uint4(rpack(v0.x, v0.y), rpack(v0.z, v0.w),       \
                                  rpack(v1.x, v1.y), rpack(v1.z, v1.w));      \
        }                                                                     \
        f32x4 acc0 = {b1v0, b1v0, b1v0, b1v0};                                \
        f32x4 acc1 = {b1v1, b1v1, b1v1, b1v1};                                \
        _Pragma("unroll")                                                     \
        for (int kb = 0; kb < 4; ++kb) {                                      \
            const bf16x8 bh0 = *(const bf16x8*)&w1s[((kb * 2 + 0) * 4 + q) * 128 + c * 8]; \
            const bf16x8 bh1 = *(const bf16x8*)&w1s[((kb * 2 + 1) * 4 + q) * 128 + c * 8]; \
            acc0 = __builtin_amdgcn_mfma_f32_16x16x32_bf16(af[kb].v, bh0, acc0, 0, 0, 0); \
            acc1 = __builtin_amdgcn_mfma_f32_16x16x32_bf16(af[kb].v, bh1, acc1, 0, 0, 0); \
        }                                                                     \
        /* relu + park h (bf16 in u32 slots) in wave-private swizzled LDS */  \
        _Pragma("unroll")                                                     \
        for (int r = 0; r < 4; ++r) {                                         \
            const int row = q * 4 + r;                                        \
            const int xsw = (row & 7) << 2;                                   \
            hw[(row * 32 + c) ^ xsw] =                                        \
                (unsigned)(unsigned short)rbf16(fmaxf(acc0[r], 0.f));         \
            hw[(row * 32 + 16 + c) ^ xsw] =                                   \
                (unsigned)(unsigned short)rbf16(fmaxf(acc1[r], 0.f));         \
        }                                                                     \
        /* layer 2 A-frag: node=c, j=q*8+e (offsets INSIDE the XOR) */        \
        const int hsw = (c & 7) << 2;                                         \
        const uint4 u0 = *(const uint4*)&hw[(c * 32 + q * 8) ^ hsw];          \
        const uint4 u1 = *(const uint4*)&hw[(c * 32 + q * 8 + 4) ^ hsw];      \
        FragU ha;                                                             \
        ha.u.x = (u0.x & 0xffffu) | (u0.y << 16);                             \
        ha.u.y = (u0.z & 0xffffu) | (u0.w << 16);                             \
        ha.u.z = (u1.x & 0xffffu) | (u1.y << 16);                             \
        ha.u.w = (u1.z & 0xffffu) | (u1.w << 16);                             \
        f32x4 lacc = {b2v, b2v, b2v, b2v};                                    \
        lacc = __builtin_amdgcn_mfma_f32_16x16x32_bf16(ha.v, w2f.v, lacc, 0, 0, 0); \
        /* softmax over K=16 (no max-subtract; |logit| small), store */       \
        float ex0 = __expf(lacc[0]);                                          \
        float ex1 = __expf(lacc[1]);                                          \
        float ex2 = __expf(lacc[2]);                                          \
        float ex3 = __expf(lacc[3]);                                          \
        float s0 = ex0, s1 = ex1, s2 = ex2, s3 = ex3;                         \
        _Pragma("unroll")                                                     \
        for (int s = 1; s < 16; s <<= 1) {                                    \
            s0 += __shfl_xor(s0, s, 16);                                      \
            s1 += __shfl_xor(s1, s, 16);                                      \
            s2 += __shfl_xor(s2, s, 16);                                      \
            s3 += __shfl_xor(s3, s, 16);                                      \
        }                                                                     \
        const size_t node0 = blockbase + (size_t)(MT) * 64 + (size_t)wave * 16 + q * 4; \
        const size_t ob = node0 * K_ + c;                                     \
        assign_out[ob + 0 * K_] = ex0 / s0;                                   \
        assign_out[ob + 1 * K_] = ex1 / s1;                                   \
        assign_out[ob + 2 * K_] = ex2 / s2;                                   \
        assign_out[ob + 3 * K_] = ex3 / s3;                                   \
        if (DO_PREF) {                                                        \
            __syncthreads();  /* drain tile reads */                          \
            _Pragma("unroll")                                                 \
            for (int i = 0; i < 8; ++i)                                       \
                *(float4*)((char*)xstage + sbyte[i]) = ld[i];                 \
            __syncthreads();  /* publish next tile */                         \
        }                                                                     \
    }

    STEP(0, 1)
    STEP(1, 1)
    STEP(2, 1)
    STEP(3, 0)

#undef STEP
}

// ---------------------------------------------------------------------------
// Kernel 2 (v4): coarse segment-sum + fused edge writer (unchanged, ~6 us).
// ---------------------------------------------------------------------------
#define FMA4(dst, v, sc)                                                      \
    dst.x = fmaf(v.x, sc, dst.x); dst.y = fmaf(v.y, sc, dst.y);               \
    dst.z = fmaf(v.z, sc, dst.z); dst.w = fmaf(v.w, sc, dst.w)

__global__ __launch_bounds__(1024, 4) void coarse_kernel(
    const float* __restrict__ x, const float* __restrict__ assign,
    const int* __restrict__ n_node, float* __restrict__ out)
{
    __shared__ float xs[2][32 * 128];
    __shared__ float as_[2][32 * 16];
    __shared__ int pref[G_];

    const int tid = threadIdx.x;
    const int g = blockIdx.x;

    if (tid < 256) {
        const int e = g * 256 + tid;
        out[OFF_SEND + e] = (float)(g * K_ + (tid >> 4));
        out[OFF_RECV + e] = (float)(g * K_ + (tid & 15));
        out[OFF_EDGE + e] = 1.0f;
    }

    if (tid < G_) pref[tid] = n_node[tid];
    __syncthreads();
    for (int st = 1; st < G_; st <<= 1) {
        int v = 0;
        if (tid < G_ && tid >= st) v = pref[tid - st];
        __syncthreads();
        if (tid < G_ && tid >= st) pref[tid] += v;
        __syncthreads();
    }
    const int start = (g == 0) ? 0 : min(pref[g - 1], N_);
    const int end   = (g == G_ - 1) ? N_ : min(pref[g], N_);

    const int dq = tid & 31;
    const int s  = tid >> 5;

    float4 acc[K_];
#pragma unroll
    for (int k = 0; k < K_; ++k) acc[k] = make_float4(0.f, 0.f, 0.f, 0.f);

    const int total = end - start;
    const int nfull = total >> 5;
    const int tail  = total & 31;

    float4 rx = make_float4(0.f, 0.f, 0.f, 0.f);
    float4 ra = make_float4(0.f, 0.f, 0.f, 0.f);
    if (nfull > 0) {
        rx = *(const float4*)(x + (size_t)start * D_ + tid * 4);
        if (tid < 128)
            ra = *(const float4*)(assign + (size_t)start * K_ + tid * 4);
    }

    int b = 0;
    for (int cc = 0; cc < nfull; ++cc) {
        *(float4*)(&xs[b][tid * 4]) = rx;
        if (tid < 128) *(float4*)(&as_[b][tid * 4]) = ra;
        __syncthreads();

        if (cc + 1 < nfull) {
            const size_t nb = (size_t)start + (size_t)(cc + 1) * 32;
            rx = *(const float4*)(x + nb * D_ + tid * 4);
            if (tid < 128)
                ra = *(const float4*)(assign + nb * K_ + tid * 4);
        }

        const float4 xv = *(const float4*)(&xs[b][s * D_ + dq * 4]);
        const float4* av = (const float4*)(&as_[b][s * K_]);
#pragma unroll
        for (int qq = 0; qq < 4; ++qq) {
            const float4 a = av[qq];
            FMA4(acc[4 * qq + 0], xv, a.x);
            FMA4(acc[4 * qq + 1], xv, a.y);
            FMA4(acc[4 * qq + 2], xv, a.z);
            FMA4(acc[4 * qq + 3], xv, a.w);
        }
        b ^= 1;
    }

    if (tail > 0 && s < tail) {
        const size_t n = (size_t)start + (size_t)nfull * 32 + s;
        const float4 xv = *(const float4*)(x + n * D_ + dq * 4);
        const float4* av = (const float4*)(assign + n * K_);
#pragma unroll
        for (int qq = 0; qq < 4; ++qq) {
            const float4 a = av[qq];
            FMA4(acc[4 * qq + 0], xv, a.x);
            FMA4(acc[4 * qq + 1], xv, a.y);
            FMA4(acc[4 * qq + 2], xv, a.z);
            FMA4(acc[4 * qq + 3], xv, a.w);
        }
    }

    __syncthreads();
    float* red = &xs[0][0];
#pragma unroll
    for (int k = 0; k < K_; ++k) {
        *(float4*)(&red[s * D_ + dq * 4]) = acc[k];
        __syncthreads();
        if (tid < D_) {
            float sum = 0.f;
#pragma unroll
            for (int ss = 0; ss < 32; ++ss) sum += red[ss * D_ + tid];
            out[OFF_COARSE + ((size_t)g * K_ + k) * D_ + tid] = sum;
        }
        __syncthreads();
    }
}

extern "C" void kernel_launch(void* const* d_in, const int* in_sizes, int n_in,
                              void* d_out, int out_size, void* d_ws, size_t ws_size,
                              hipStream_t stream)
{
    const float* x      = (const float*)d_in[0];
    const float* W1     = (const float*)d_in[1];
    const float* b1     = (const float*)d_in[2];
    const float* W2     = (const float*)d_in[3];
    const float* b2     = (const float*)d_in[4];
    const int*   n_node = (const int*)d_in[5];
    float* out = (float*)d_out;

    mlp_assign_mfma<<<N_ / 256, 256, 0, stream>>>(x, W1, b1, W2, b2, out + OFF_ASSIGN);
    coarse_kernel<<<G_, 1024, 0, stream>>>(x, out + OFF_ASSIGN, n_node, out);
}